// Round 1
// 406.768 us; speedup vs baseline: 1.0324x; 1.0324x over previous
//
#include <hip/hip_runtime.h>

// MultiHeadAttentionBlock: B=4, S=2048, D=1024, H=16, DK=64
// Pipeline: cvt(w); cvt(q,k,v) [k,v staged in d_out - dead until final gemm];
// batched QKV gemm (1 dispatch, 1536 blocks); flash attention (transposed,
// no-max softmax); out gemm -> fp32.
// All matmuls: bf16 MFMA 16x16x32, fp32 accumulate, GLL16 staging.
//
// Verified MFMA layouts (learn_hip m89/m91):
//   A-operand: lane holds A[m=lane&15][k=(lane>>4)*8 + j], j=0..7 (16B contiguous)
//   B-operand: lane holds B^T-row n=lane&15 along k (same shape as A)
//   C/D:       col = lane&15 (B index), row = (lane>>4)*4 + reg (A index)

typedef __attribute__((ext_vector_type(8))) short bf16x8;
typedef __attribute__((ext_vector_type(4))) float f32x4;
typedef unsigned int u32;

#define DEVI __device__ __forceinline__

static constexpr int S_LEN = 2048;
static constexpr int NH = 16;
static constexpr int DK = 64;
// scores scale folded into Q projection: (1/sqrt(64)) * log2(e)
static constexpr float Q_SCALE = 0.125f * 1.44269504088896340736f;

DEVI unsigned short f2b(float f) {  // fp32 -> bf16 round-to-nearest-even
    unsigned int u = __builtin_bit_cast(unsigned int, f);
    u += 0x7fffu + ((u >> 16) & 1u);
    return (unsigned short)(u >> 16);
}

// pack two fp32 -> bf16x2 in one HW inst when available (gfx950 v_cvt_pk_bf16_f32)
DEVI u32 pkbf16(float a, float b) {
#if __has_builtin(__builtin_amdgcn_cvt_pk_bf16_f32)
    auto r = __builtin_amdgcn_cvt_pk_bf16_f32(a, b);
    return __builtin_bit_cast(u32, r);
#else
    return (u32)f2b(a) | ((u32)f2b(b) << 16);
#endif
}

DEVI f32x4 mfma16(bf16x8 a, bf16x8 b, f32x4 c) {
    return __builtin_amdgcn_mfma_f32_16x16x32_bf16(a, b, c, 0, 0, 0);
}

#define GLL16(g, l)                                                        \
    __builtin_amdgcn_global_load_lds(                                      \
        (const __attribute__((address_space(1))) u32*)(g),                 \
        (__attribute__((address_space(3))) u32*)(l), 16, 0, 0)

// ---------------------------------------------------------------------------
// fp32 -> bf16 converters (memory-bound)
// ---------------------------------------------------------------------------
__global__ __launch_bounds__(256) void cvt3(
    const float* __restrict__ q, const float* __restrict__ k,
    const float* __restrict__ v, unsigned short* __restrict__ dq,
    unsigned short* __restrict__ dk, unsigned short* __restrict__ dv) {
    const int z = blockIdx.y;
    const float* src = z == 0 ? q : z == 1 ? k : v;
    unsigned short* dst = z == 0 ? dq : z == 1 ? dk : dv;
    long i = ((long)blockIdx.x * 256 + threadIdx.x) * 8;
    float4 v0 = *(const float4*)(src + i);
    float4 v1 = *(const float4*)(src + i + 4);
    uint4 o;
    o.x = pkbf16(v0.x, v0.y);
    o.y = pkbf16(v0.z, v0.w);
    o.z = pkbf16(v1.x, v1.y);
    o.w = pkbf16(v1.z, v1.w);
    *(uint4*)(dst + i) = o;
}

__global__ __launch_bounds__(256) void cvt_w(
    const float* __restrict__ a, const float* __restrict__ b,
    const float* __restrict__ c, const float* __restrict__ d,
    unsigned short* __restrict__ o) {
    const float* src = blockIdx.y == 0 ? a : blockIdx.y == 1 ? b
                     : blockIdx.y == 2 ? c : d;
    unsigned short* dst = o + (long)blockIdx.y * 1048576;
    long i = ((long)blockIdx.x * 256 + threadIdx.x) * 8;
    float4 v0 = *(const float4*)(src + i);
    float4 v1 = *(const float4*)(src + i + 4);
    uint4 ov;
    ov.x = pkbf16(v0.x, v0.y);
    ov.y = pkbf16(v0.z, v0.w);
    ov.z = pkbf16(v1.x, v1.y);
    ov.w = pkbf16(v1.z, v1.w);
    *(uint4*)(dst + i) = ov;
}

// ---------------------------------------------------------------------------
// Batched QKV GEMM: z=0: qh=(q@wq^T+bq)*Q_SCALE  [B,H,S,DK]
//                   z=1: kh= k@wk^T+bk           [B,H,S,DK]
//                   z=2: vht=(v@wv^T+bv)^T       [B,H,DK,S]
// 128x128 tile, BK=32, GLL16 double-buffered, XOR-swizzled LDS.
// ---------------------------------------------------------------------------
__global__ __launch_bounds__(256) void gemm_qkv(
    const unsigned short* __restrict__ aq, const unsigned short* __restrict__ ak,
    const unsigned short* __restrict__ av, const unsigned short* __restrict__ wqkv,
    const float* __restrict__ bq, const float* __restrict__ bk,
    const float* __restrict__ bv, unsigned short* __restrict__ qh,
    unsigned short* __restrict__ kh, unsigned short* __restrict__ vht) {
    __shared__ __align__(16) unsigned short As[2][128 * 32];
    __shared__ __align__(16) unsigned short Bs[2][128 * 32];
    const int tid = threadIdx.x;
    const int w = tid >> 6, l = tid & 63, l16 = l & 15, quad = l >> 4;
    const int wm = (w >> 1) * 64, wn = (w & 1) * 64;
    const int m0 = blockIdx.y * 128, n0 = blockIdx.x * 128;
    const int z = blockIdx.z;
    const unsigned short* A = z == 0 ? aq : z == 1 ? ak : av;
    const unsigned short* W = wqkv + (long)z * 1048576;
    const float* bias = z == 0 ? bq : z == 1 ? bk : bv;

    f32x4 acc[4][4] = {};

    auto stage = [&](int kt, int buf) {
        #pragma unroll
        for (int h = 0; h < 2; ++h) {
            int sb = h * 256 + w * 64;
            int slot = sb + l;
            int row = slot >> 2, c = (slot & 3) ^ ((row >> 1) & 3);
            GLL16(A + (long)(m0 + row) * 1024 + kt + c * 8, &As[buf][sb * 8]);
            GLL16(W + (long)(n0 + row) * 1024 + kt + c * 8, &Bs[buf][sb * 8]);
        }
    };

    stage(0, 0);
    __syncthreads();

    for (int ki = 0; ki < 32; ++ki) {
        if (ki < 31) stage((ki + 1) * 32, (ki + 1) & 1);
        const unsigned short* as = As[ki & 1];
        const unsigned short* bs = Bs[ki & 1];
        bf16x8 a[4], b[4];
        #pragma unroll
        for (int i = 0; i < 4; ++i) {
            int r = wm + i * 16 + l16;
            a[i] = *(const bf16x8*)(as + (r * 4 + (quad ^ ((r >> 1) & 3))) * 8);
        }
        #pragma unroll
        for (int j = 0; j < 4; ++j) {
            int r = wn + j * 16 + l16;
            b[j] = *(const bf16x8*)(bs + (r * 4 + (quad ^ ((r >> 1) & 3))) * 8);
        }
        #pragma unroll
        for (int i = 0; i < 4; ++i)
            #pragma unroll
            for (int j = 0; j < 4; ++j)
                acc[i][j] = mfma16(a[i], b[j], acc[i][j]);
        __syncthreads();  // drains GLL16 vmcnt + protects buf reuse
    }

    if (z < 2) {
        unsigned short* out = z == 0 ? qh : kh;
        const float scale = z == 0 ? Q_SCALE : 1.0f;
        #pragma unroll
        for (int j = 0; j < 4; ++j) {
            int n = n0 + wn + j * 16 + l16;
            float bvl = bias[n];
            int hh = n >> 6, dd = n & 63;
            #pragma unroll
            for (int i = 0; i < 4; ++i)
                #pragma unroll
                for (int r = 0; r < 4; ++r) {
                    int m = m0 + wm + i * 16 + quad * 4 + r;
                    int bb = m >> 11, ss = m & 2047;
                    out[(((long)(bb * NH + hh) * S_LEN + ss) * DK) + dd] =
                        f2b((acc[i][j][r] + bvl) * scale);
                }
        }
    } else {
        unsigned short* out = vht;  // [bh][d][s]
        #pragma unroll
        for (int j = 0; j < 4; ++j) {
            int n = n0 + wn + j * 16 + l16;
            float bvl = bias[n];
            int hh = n >> 6, dd = n & 63;
            #pragma unroll
            for (int i = 0; i < 4; ++i) {
                int m = m0 + wm + i * 16 + quad * 4;  // r=0..3 contiguous in s
                int bb = m >> 11, ss = m & 2047;
                uint2 pk;
                pk.x = pkbf16(acc[i][j][0] + bvl, acc[i][j][1] + bvl);
                pk.y = pkbf16(acc[i][j][2] + bvl, acc[i][j][3] + bvl);
                *(uint2*)(out + ((long)(bb * NH + hh) * DK + dd) * S_LEN + ss) = pk;
            }
        }
    }
}

// ---------------------------------------------------------------------------
// Output GEMM: fp32 out[m,n] = ctx@wo^T + bo
// ---------------------------------------------------------------------------
__global__ __launch_bounds__(256) void gemm_out(
    const unsigned short* __restrict__ A, const unsigned short* __restrict__ W,
    const float* __restrict__ bias, float* __restrict__ out) {
    __shared__ __align__(16) unsigned short As[2][128 * 32];
    __shared__ __align__(16) unsigned short Bs[2][128 * 32];
    const int tid = threadIdx.x;
    const int w = tid >> 6, l = tid & 63, l16 = l & 15, quad = l >> 4;
    const int wm = (w >> 1) * 64, wn = (w & 1) * 64;
    const int m0 = blockIdx.y * 128, n0 = blockIdx.x * 128;

    f32x4 acc[4][4] = {};

    auto stage = [&](int kt, int buf) {
        #pragma unroll
        for (int h = 0; h < 2; ++h) {
            int sb = h * 256 + w * 64;
            int slot = sb + l;
            int row = slot >> 2, c = (slot & 3) ^ ((row >> 1) & 3);
            GLL16(A + (long)(m0 + row) * 1024 + kt + c * 8, &As[buf][sb * 8]);
            GLL16(W + (long)(n0 + row) * 1024 + kt + c * 8, &Bs[buf][sb * 8]);
        }
    };

    stage(0, 0);
    __syncthreads();

    for (int ki = 0; ki < 32; ++ki) {
        if (ki < 31) stage((ki + 1) * 32, (ki + 1) & 1);
        const unsigned short* as = As[ki & 1];
        const unsigned short* bs = Bs[ki & 1];
        bf16x8 a[4], b[4];
        #pragma unroll
        for (int i = 0; i < 4; ++i) {
            int r = wm + i * 16 + l16;
            a[i] = *(const bf16x8*)(as + (r * 4 + (quad ^ ((r >> 1) & 3))) * 8);
        }
        #pragma unroll
        for (int j = 0; j < 4; ++j) {
            int r = wn + j * 16 + l16;
            b[j] = *(const bf16x8*)(bs + (r * 4 + (quad ^ ((r >> 1) & 3))) * 8);
        }
        #pragma unroll
        for (int i = 0; i < 4; ++i)
            #pragma unroll
            for (int j = 0; j < 4; ++j)
                acc[i][j] = mfma16(a[i], b[j], acc[i][j]);
        __syncthreads();
    }

    #pragma unroll
    for (int j = 0; j < 4; ++j) {
        int n = n0 + wn + j * 16 + l16;
        float bv = bias[n];
        #pragma unroll
        for (int i = 0; i < 4; ++i)
            #pragma unroll
            for (int r = 0; r < 4; ++r) {
                int m = m0 + wm + i * 16 + quad * 4 + r;
                out[(long)m * 1024 + n] = acc[i][j][r] + bv;
            }
    }
}

// ---------------------------------------------------------------------------
// Flash attention, transposed formulation.
//   S^T = K_tile . Q^T ; p = exp2(s) (Q pre-scaled, no max subtraction);
//   P 32-key halves through wave-private LDS rows; O^T = V^T . P^T.
//
// Round 1 change: key-tile 128 -> 64 so LDS = 16384 (Kb dbuf) + 8192 (Vb)
// + 11264 (P) = 35840 B  ->  4 blocks/CU (was 60416 B -> 2 blocks/CU,
// occupancy 19.7%). All 1024 blocks co-resident. Q-tile stays 128; kt loop
// 16 -> 32 iters; per-thread MFMA/exp2/LDS totals unchanged.
// XCD swizzle: all 16 q-tiles of a head on one XCD (8 heads x 512 KB = L2).
// ---------------------------------------------------------------------------
__global__ __launch_bounds__(256, 4) void attn(
    const unsigned short* __restrict__ qh, const unsigned short* __restrict__ kh,
    const unsigned short* __restrict__ vht, unsigned short* __restrict__ ctx) {
    __shared__ __align__(16) unsigned short Kb[2][4096];   // [64 keys][64 d] swz
    __shared__ __align__(16) unsigned short Vb[4096];      // [64 d][64 keys] swz
    __shared__ __align__(16) unsigned short P[128 * 44];

    // XCD-aware swizzle: 1024 blocks, 1024 % 8 == 0 -> bijective.
    // id2 chunks of 128 per XCD = 8 heads x 16 q-tiles.
    const int id = blockIdx.y * 16 + blockIdx.x;
    const int id2 = (id & 7) * 128 + (id >> 3);
    const int qt = id2 & 15, bh = id2 >> 4;
    const int tid = threadIdx.x;
    const int w = tid >> 6, l = tid & 63, l16 = l & 15, quad = l >> 4;

    const unsigned short* kh_b = kh + (long)bh * 2048 * 64;
    const unsigned short* vh_b = vht + (long)bh * 64 * 2048;

    const unsigned short* qsrc = qh + ((long)bh * 2048 + qt * 128) * 64;
    bf16x8 qf[2][2];
    #pragma unroll
    for (int dd = 0; dd < 2; ++dd)
        #pragma unroll
        for (int i = 0; i < 2; ++i)
            qf[dd][i] = *(const bf16x8*)(qsrc + (w * 32 + i * 16 + l16) * 64 +
                                         dd * 32 + quad * 8);

    // stage K tile (64 rows x 64 d = 512 slots of 16B, 2 per thread)
    auto stage_k = [&](const unsigned short* base, int buf) {
        #pragma unroll
        for (int rr = 0; rr < 2; ++rr) {
            int sb = rr * 256 + w * 64;
            int slot = sb + l;
            int row = slot >> 3, cc = (slot & 7) ^ (row & 7);
            GLL16(base + (long)row * 64 + cc * 8, &Kb[buf][sb * 8]);
        }
    };
    // stage V^T tile (64 d x 64 keys)
    auto stage_v = [&](const unsigned short* vbase) {
        #pragma unroll
        for (int rr = 0; rr < 2; ++rr) {
            int sb = rr * 256 + w * 64;
            int slot = sb + l;
            int d = slot >> 3, cc = (slot & 7) ^ (d & 7);
            GLL16(vbase + (long)d * 2048 + cc * 8, &Vb[sb * 8]);
        }
    };

    stage_k(kh_b, 0);
    __syncthreads();

    f32x4 o[4][2] = {};
    float lsum[2] = {0.f, 0.f};

    for (int kt = 0; kt < 32; ++kt) {
        if (kt < 31) stage_k(kh_b + (long)(kt + 1) * 64 * 64, (kt + 1) & 1);
        stage_v(vh_b + kt * 64);

        const unsigned short* kb = Kb[kt & 1];
        f32x4 sa[2][4] = {};
        #pragma unroll
        for (int dd = 0; dd < 2; ++dd) {
            bf16x8 kf[4];
            #pragma unroll
            for (int ja = 0; ja < 4; ++ja) {
                int row = ja * 16 + l16;
                kf[ja] = *(const bf16x8*)(kb + (row * 8 + ((dd * 4 + quad) ^ (row & 7))) * 8);
            }
            #pragma unroll
            for (int i = 0; i < 2; ++i)
                #pragma unroll
                for (int ja = 0; ja < 4; ++ja)
                    sa[i][ja] = mfma16(kf[ja], qf[dd][i], sa[i][ja]);
        }

        #pragma unroll
        for (int i = 0; i < 2; ++i)
            #pragma unroll
            for (int ja = 0; ja < 4; ++ja)
                #pragma unroll
                for (int r = 0; r < 4; ++r) {
                    float p = exp2f(sa[i][ja][r]);
                    sa[i][ja][r] = p;
                    lsum[i] += p;
                }

        __syncthreads();  // V[kt] + K[kt+1] arrived (vmcnt drain before barrier)

        #pragma unroll
        for (int qtr = 0; qtr < 2; ++qtr) {
            #pragma unroll
            for (int jh = 0; jh < 2; ++jh)
                #pragma unroll
                for (int i = 0; i < 2; ++i) {
                    int row = w * 32 + i * 16 + l16;
                    int ja = qtr * 2 + jh;
                    uint2 pk;
                    pk.x = pkbf16(sa[i][ja][0], sa[i][ja][1]);
                    pk.y = pkbf16(sa[i][ja][2], sa[i][ja][3]);
                    *(uint2*)(&P[row * 44 + jh * 16 + quad * 4]) = pk;
                }
            bf16x8 vf[4], pf[2];
            #pragma unroll
            for (int jd = 0; jd < 4; ++jd) {
                int d = jd * 16 + l16;
                vf[jd] = *(const bf16x8*)(Vb + (d * 8 + ((qtr * 4 + quad) ^ (d & 7))) * 8);
            }
            #pragma unroll
            for (int i = 0; i < 2; ++i) {
                int row = w * 32 + i * 16 + l16;
                pf[i] = *(const bf16x8*)(&P[row * 44 + quad * 8]);
            }
            #pragma unroll
            for (int jd = 0; jd < 4; ++jd)
                #pragma unroll
                for (int i = 0; i < 2; ++i)
                    o[jd][i] = mfma16(vf[jd], pf[i], o[jd][i]);
        }
        __syncthreads();  // all waves done reading Vb before next stage_v
    }

    #pragma unroll
    for (int i = 0; i < 2; ++i) {
        lsum[i] += __shfl_xor(lsum[i], 16);
        lsum[i] += __shfl_xor(lsum[i], 32);
    }

    const int b = bh >> 4, hh = bh & 15;
    #pragma unroll
    for (int i = 0; i < 2; ++i) {
        float inv = 1.0f / lsum[i];
        int s = qt * 128 + w * 32 + i * 16 + l16;
        #pragma unroll
        for (int jd = 0; jd < 4; ++jd) {
            uint2 pk;
            pk.x = pkbf16(o[jd][i][0] * inv, o[jd][i][1] * inv);
            pk.y = pkbf16(o[jd][i][2] * inv, o[jd][i][3] * inv);
            *(uint2*)(&ctx[((long)(b * 2048 + s) * 1024) + hh * 64 + jd * 16 + quad * 4]) = pk;
        }
    }
}

extern "C" void kernel_launch(void* const* d_in, const int* in_sizes, int n_in,
                              void* d_out, int out_size, void* d_ws, size_t ws_size,
                              hipStream_t stream) {
    const float* q  = (const float*)d_in[0];
    const float* k  = (const float*)d_in[1];
    const float* v  = (const float*)d_in[2];
    const float* wq = (const float*)d_in[3];
    const float* bq = (const float*)d_in[4];
    const float* wk = (const float*)d_in[5];
    const float* bk = (const float*)d_in[6];
    const float* wv = (const float*)d_in[7];
    const float* bv = (const float*)d_in[8];
    const float* wo = (const float*)d_in[9];
    const float* bo = (const float*)d_in[10];
    float* out = (float*)d_out;

    // workspace (u16 units): ab_q(8M, reused as ctx) | qh(8M) | kh(8M) |
    // vht(8M) | weights 4x1M  = 36M u16 = 72 MB.
    // ab_k/ab_v live in d_out (32 MB fp32 = 16M u16), dead until gemm_out.
    const size_t NE = 8u * 1024u * 1024u;
    unsigned short* ab_q = (unsigned short*)d_ws;
    unsigned short* qh   = ab_q + NE;
    unsigned short* kh   = qh + NE;
    unsigned short* vht  = kh + NE;
    unsigned short* wb   = vht + NE;
    unsigned short* wob  = wb + 3 * 1048576;
    unsigned short* ctx  = ab_q;
    unsigned short* ab_k = (unsigned short*)d_out;
    unsigned short* ab_v = ab_k + NE;

    dim3 blk(256);
    cvt_w<<<dim3(512, 4), blk, 0, stream>>>(wq, wk, wv, wo, wb);
    cvt3<<<dim3(4096, 3), blk, 0, stream>>>(q, k, v, ab_q, ab_k, ab_v);
    gemm_qkv<<<dim3(8, 64, 3), blk, 0, stream>>>(ab_q, ab_k, ab_v, wb,
                                                 bq, bk, bv, qh, kh, vht);
    attn<<<dim3(16, 64), blk, 0, stream>>>(qh, kh, vht, ctx);
    gemm_out<<<dim3(8, 64), blk, 0, stream>>>(ctx, wob, bo, out);
}

// Round 2
// 376.244 us; speedup vs baseline: 1.1161x; 1.0811x over previous
//
#include <hip/hip_runtime.h>

// MultiHeadAttentionBlock: B=4, S=2048, D=1024, H=16, DK=64
// Pipeline: cvt(w); cvt(q,k,v) [k,v staged in d_out - dead until final gemm];
// batched QKV gemm (1 dispatch, 1536 blocks); flash attention (transposed,
// no-max softmax); out gemm -> fp32.
// All matmuls: bf16 MFMA 16x16x32, fp32 accumulate, GLL16 staging.
//
// Verified MFMA layouts (learn_hip m89/m91):
//   A-operand: lane holds A[m=lane&15][k=(lane>>4)*8 + j], j=0..7 (16B contiguous)
//   B-operand: lane holds B^T-row n=lane&15 along k (same shape as A)
//   C/D:       col = lane&15 (B index), row = (lane>>4)*4 + reg (A index)

typedef __attribute__((ext_vector_type(8))) short bf16x8;
typedef __attribute__((ext_vector_type(4))) float f32x4;
typedef unsigned int u32;

#define DEVI __device__ __forceinline__

static constexpr int S_LEN = 2048;
static constexpr int NH = 16;
static constexpr int DK = 64;
// scores scale folded into Q projection: (1/sqrt(64)) * log2(e)
static constexpr float Q_SCALE = 0.125f * 1.44269504088896340736f;

DEVI unsigned short f2b(float f) {  // fp32 -> bf16 round-to-nearest-even
    unsigned int u = __builtin_bit_cast(unsigned int, f);
    u += 0x7fffu + ((u >> 16) & 1u);
    return (unsigned short)(u >> 16);
}

// pack two fp32 -> bf16x2 in one HW inst when available (gfx950 v_cvt_pk_bf16_f32)
DEVI u32 pkbf16(float a, float b) {
#if __has_builtin(__builtin_amdgcn_cvt_pk_bf16_f32)
    auto r = __builtin_amdgcn_cvt_pk_bf16_f32(a, b);
    return __builtin_bit_cast(u32, r);
#else
    return (u32)f2b(a) | ((u32)f2b(b) << 16);
#endif
}

// raw v_exp_f32: no OCML denormal/range fixup (inputs here are |x| <~ 12;
// denormal-result flush-to-zero is correct behavior for softmax weights)
DEVI float fexp2(float x) {
#if __has_builtin(__builtin_amdgcn_exp2f)
    return __builtin_amdgcn_exp2f(x);
#else
    return exp2f(x);
#endif
}

DEVI f32x4 mfma16(bf16x8 a, bf16x8 b, f32x4 c) {
    return __builtin_amdgcn_mfma_f32_16x16x32_bf16(a, b, c, 0, 0, 0);
}

#define GLL16(g, l)                                                        \
    __builtin_amdgcn_global_load_lds(                                      \
        (const __attribute__((address_space(1))) u32*)(g),                 \
        (__attribute__((address_space(3))) u32*)(l), 16, 0, 0)

// ---------------------------------------------------------------------------
// fp32 -> bf16 converters (memory-bound)
// ---------------------------------------------------------------------------
__global__ __launch_bounds__(256) void cvt3(
    const float* __restrict__ q, const float* __restrict__ k,
    const float* __restrict__ v, unsigned short* __restrict__ dq,
    unsigned short* __restrict__ dk, unsigned short* __restrict__ dv) {
    const int z = blockIdx.y;
    const float* src = z == 0 ? q : z == 1 ? k : v;
    unsigned short* dst = z == 0 ? dq : z == 1 ? dk : dv;
    long i = ((long)blockIdx.x * 256 + threadIdx.x) * 8;
    float4 v0 = *(const float4*)(src + i);
    float4 v1 = *(const float4*)(src + i + 4);
    uint4 o;
    o.x = pkbf16(v0.x, v0.y);
    o.y = pkbf16(v0.z, v0.w);
    o.z = pkbf16(v1.x, v1.y);
    o.w = pkbf16(v1.z, v1.w);
    *(uint4*)(dst + i) = o;
}

__global__ __launch_bounds__(256) void cvt_w(
    const float* __restrict__ a, const float* __restrict__ b,
    const float* __restrict__ c, const float* __restrict__ d,
    unsigned short* __restrict__ o) {
    const float* src = blockIdx.y == 0 ? a : blockIdx.y == 1 ? b
                     : blockIdx.y == 2 ? c : d;
    unsigned short* dst = o + (long)blockIdx.y * 1048576;
    long i = ((long)blockIdx.x * 256 + threadIdx.x) * 8;
    float4 v0 = *(const float4*)(src + i);
    float4 v1 = *(const float4*)(src + i + 4);
    uint4 ov;
    ov.x = pkbf16(v0.x, v0.y);
    ov.y = pkbf16(v0.z, v0.w);
    ov.z = pkbf16(v1.x, v1.y);
    ov.w = pkbf16(v1.z, v1.w);
    *(uint4*)(dst + i) = ov;
}

// ---------------------------------------------------------------------------
// Batched QKV GEMM: z=0: qh=(q@wq^T+bq)*Q_SCALE  [B,H,S,DK]
//                   z=1: kh= k@wk^T+bk           [B,H,S,DK]
//                   z=2: vht=(v@wv^T+bv)^T       [B,H,DK,S]
// 128x128 tile, BK=32, GLL16 double-buffered, XOR-swizzled LDS.
// ---------------------------------------------------------------------------
__global__ __launch_bounds__(256) void gemm_qkv(
    const unsigned short* __restrict__ aq, const unsigned short* __restrict__ ak,
    const unsigned short* __restrict__ av, const unsigned short* __restrict__ wqkv,
    const float* __restrict__ bq, const float* __restrict__ bk,
    const float* __restrict__ bv, unsigned short* __restrict__ qh,
    unsigned short* __restrict__ kh, unsigned short* __restrict__ vht) {
    __shared__ __align__(16) unsigned short As[2][128 * 32];
    __shared__ __align__(16) unsigned short Bs[2][128 * 32];
    const int tid = threadIdx.x;
    const int w = tid >> 6, l = tid & 63, l16 = l & 15, quad = l >> 4;
    const int wm = (w >> 1) * 64, wn = (w & 1) * 64;
    const int m0 = blockIdx.y * 128, n0 = blockIdx.x * 128;
    const int z = blockIdx.z;
    const unsigned short* A = z == 0 ? aq : z == 1 ? ak : av;
    const unsigned short* W = wqkv + (long)z * 1048576;
    const float* bias = z == 0 ? bq : z == 1 ? bk : bv;

    f32x4 acc[4][4] = {};

    auto stage = [&](int kt, int buf) {
        #pragma unroll
        for (int h = 0; h < 2; ++h) {
            int sb = h * 256 + w * 64;
            int slot = sb + l;
            int row = slot >> 2, c = (slot & 3) ^ ((row >> 1) & 3);
            GLL16(A + (long)(m0 + row) * 1024 + kt + c * 8, &As[buf][sb * 8]);
            GLL16(W + (long)(n0 + row) * 1024 + kt + c * 8, &Bs[buf][sb * 8]);
        }
    };

    stage(0, 0);
    __syncthreads();

    for (int ki = 0; ki < 32; ++ki) {
        if (ki < 31) stage((ki + 1) * 32, (ki + 1) & 1);
        const unsigned short* as = As[ki & 1];
        const unsigned short* bs = Bs[ki & 1];
        bf16x8 a[4], b[4];
        #pragma unroll
        for (int i = 0; i < 4; ++i) {
            int r = wm + i * 16 + l16;
            a[i] = *(const bf16x8*)(as + (r * 4 + (quad ^ ((r >> 1) & 3))) * 8);
        }
        #pragma unroll
        for (int j = 0; j < 4; ++j) {
            int r = wn + j * 16 + l16;
            b[j] = *(const bf16x8*)(bs + (r * 4 + (quad ^ ((r >> 1) & 3))) * 8);
        }
        #pragma unroll
        for (int i = 0; i < 4; ++i)
            #pragma unroll
            for (int j = 0; j < 4; ++j)
                acc[i][j] = mfma16(a[i], b[j], acc[i][j]);
        __syncthreads();  // drains GLL16 vmcnt + protects buf reuse
    }

    if (z < 2) {
        unsigned short* out = z == 0 ? qh : kh;
        const float scale = z == 0 ? Q_SCALE : 1.0f;
        #pragma unroll
        for (int j = 0; j < 4; ++j) {
            int n = n0 + wn + j * 16 + l16;
            float bvl = bias[n];
            int hh = n >> 6, dd = n & 63;
            #pragma unroll
            for (int i = 0; i < 4; ++i)
                #pragma unroll
                for (int r = 0; r < 4; ++r) {
                    int m = m0 + wm + i * 16 + quad * 4 + r;
                    int bb = m >> 11, ss = m & 2047;
                    out[(((long)(bb * NH + hh) * S_LEN + ss) * DK) + dd] =
                        f2b((acc[i][j][r] + bvl) * scale);
                }
        }
    } else {
        unsigned short* out = vht;  // [bh][d][s]
        #pragma unroll
        for (int j = 0; j < 4; ++j) {
            int n = n0 + wn + j * 16 + l16;
            float bvl = bias[n];
            int hh = n >> 6, dd = n & 63;
            #pragma unroll
            for (int i = 0; i < 4; ++i) {
                int m = m0 + wm + i * 16 + quad * 4;  // r=0..3 contiguous in s
                int bb = m >> 11, ss = m & 2047;
                uint2 pk;
                pk.x = pkbf16(acc[i][j][0] + bvl, acc[i][j][1] + bvl);
                pk.y = pkbf16(acc[i][j][2] + bvl, acc[i][j][3] + bvl);
                *(uint2*)(out + ((long)(bb * NH + hh) * DK + dd) * S_LEN + ss) = pk;
            }
        }
    }
}

// ---------------------------------------------------------------------------
// Output GEMM: fp32 out[m,n] = ctx@wo^T + bo
// ---------------------------------------------------------------------------
__global__ __launch_bounds__(256) void gemm_out(
    const unsigned short* __restrict__ A, const unsigned short* __restrict__ W,
    const float* __restrict__ bias, float* __restrict__ out) {
    __shared__ __align__(16) unsigned short As[2][128 * 32];
    __shared__ __align__(16) unsigned short Bs[2][128 * 32];
    const int tid = threadIdx.x;
    const int w = tid >> 6, l = tid & 63, l16 = l & 15, quad = l >> 4;
    const int wm = (w >> 1) * 64, wn = (w & 1) * 64;
    const int m0 = blockIdx.y * 128, n0 = blockIdx.x * 128;

    f32x4 acc[4][4] = {};

    auto stage = [&](int kt, int buf) {
        #pragma unroll
        for (int h = 0; h < 2; ++h) {
            int sb = h * 256 + w * 64;
            int slot = sb + l;
            int row = slot >> 2, c = (slot & 3) ^ ((row >> 1) & 3);
            GLL16(A + (long)(m0 + row) * 1024 + kt + c * 8, &As[buf][sb * 8]);
            GLL16(W + (long)(n0 + row) * 1024 + kt + c * 8, &Bs[buf][sb * 8]);
        }
    };

    stage(0, 0);
    __syncthreads();

    for (int ki = 0; ki < 32; ++ki) {
        if (ki < 31) stage((ki + 1) * 32, (ki + 1) & 1);
        const unsigned short* as = As[ki & 1];
        const unsigned short* bs = Bs[ki & 1];
        bf16x8 a[4], b[4];
        #pragma unroll
        for (int i = 0; i < 4; ++i) {
            int r = wm + i * 16 + l16;
            a[i] = *(const bf16x8*)(as + (r * 4 + (quad ^ ((r >> 1) & 3))) * 8);
        }
        #pragma unroll
        for (int j = 0; j < 4; ++j) {
            int r = wn + j * 16 + l16;
            b[j] = *(const bf16x8*)(bs + (r * 4 + (quad ^ ((r >> 1) & 3))) * 8);
        }
        #pragma unroll
        for (int i = 0; i < 4; ++i)
            #pragma unroll
            for (int j = 0; j < 4; ++j)
                acc[i][j] = mfma16(a[i], b[j], acc[i][j]);
        __syncthreads();
    }

    #pragma unroll
    for (int j = 0; j < 4; ++j) {
        int n = n0 + wn + j * 16 + l16;
        float bv = bias[n];
        #pragma unroll
        for (int i = 0; i < 4; ++i)
            #pragma unroll
            for (int r = 0; r < 4; ++r) {
                int m = m0 + wm + i * 16 + quad * 4 + r;
                out[(long)m * 1024 + n] = acc[i][j][r] + bv;
            }
    }
}

// ---------------------------------------------------------------------------
// Flash attention, transposed formulation.
//   S^T = K_tile . Q^T ; p = exp2(s) (Q pre-scaled, no max subtraction);
//   P 32-key halves through wave-private LDS rows; O^T = V^T . P^T.
//
// Round 2 changes (VALU-bound per R1 post-mortem: VALUBusy 61%, MfmaUtil 19%,
// occupancy doubling gave zero speedup):
//  1. raw v_exp_f32 (__builtin_amdgcn_exp2f) instead of libm exp2f — drops
//     ~4 OCML fixup VALU ops per score element (32 elems/kt).
//  2. lsum via ones-vector MFMA on the idle matrix pipe: osum = mfma(1, pf)
//     replaces 32 VALU adds/kt AND the final cross-lane shuffles (MFMA
//     broadcasts row-sums to all lanes). Denominator now sums the same
//     bf16-rounded P the numerator uses.
//  3. ONE barrier per kt (was 2): V triple-buffered, K double-buffered.
//     Writer stage_v(kt+3)->Vb[kt%3] (interval B(kt+1)..B(kt+2)) vs reader
//     PV(kt) (interval B(kt)..B(kt+1)) — separated by B(kt+1). V staged a
//     full iteration ahead of use (extra GLL16 latency cover).
// LDS: 16384 (Kb x2) + 24576 (Vb x3) + 11264 (P) = 52224 B -> 3 blocks/CU.
// XCD swizzle kept (R1: FETCH 139->32 MB).
// ---------------------------------------------------------------------------
__global__ __launch_bounds__(256, 3) void attn(
    const unsigned short* __restrict__ qh, const unsigned short* __restrict__ kh,
    const unsigned short* __restrict__ vht, unsigned short* __restrict__ ctx) {
    __shared__ __align__(16) unsigned short Kb[2][4096];   // [64 keys][64 d] swz
    __shared__ __align__(16) unsigned short Vb[3][4096];   // [64 d][64 keys] swz
    __shared__ __align__(16) unsigned short P[128 * 44];

    // XCD-aware swizzle: 1024 blocks, 1024 % 8 == 0 -> bijective.
    // 128 blocks/XCD = 8 heads x 16 q-tiles (head's K/V panel L2-resident).
    const int id = blockIdx.y * 16 + blockIdx.x;
    const int id2 = (id & 7) * 128 + (id >> 3);
    const int qt = id2 & 15, bh = id2 >> 4;
    const int tid = threadIdx.x;
    const int w = tid >> 6, l = tid & 63, l16 = l & 15, quad = l >> 4;

    const unsigned short* kh_b = kh + (long)bh * 2048 * 64;
    const unsigned short* vh_b = vht + (long)bh * 64 * 2048;

    const unsigned short* qsrc = qh + ((long)bh * 2048 + qt * 128) * 64;
    bf16x8 qf[2][2];
    #pragma unroll
    for (int dd = 0; dd < 2; ++dd)
        #pragma unroll
        for (int i = 0; i < 2; ++i)
            qf[dd][i] = *(const bf16x8*)(qsrc + (w * 32 + i * 16 + l16) * 64 +
                                         dd * 32 + quad * 8);

    // stage K tile (64 rows x 64 d = 512 slots of 16B, 2 per thread)
    auto stage_k = [&](const unsigned short* base, int buf) {
        #pragma unroll
        for (int rr = 0; rr < 2; ++rr) {
            int sb = rr * 256 + w * 64;
            int slot = sb + l;
            int row = slot >> 3, cc = (slot & 7) ^ (row & 7);
            GLL16(base + (long)row * 64 + cc * 8, &Kb[buf][sb * 8]);
        }
    };
    // stage V^T tile (64 d x 64 keys)
    auto stage_v = [&](const unsigned short* vbase, int buf) {
        #pragma unroll
        for (int rr = 0; rr < 2; ++rr) {
            int sb = rr * 256 + w * 64;
            int slot = sb + l;
            int d = slot >> 3, cc = (slot & 7) ^ (d & 7);
            GLL16(vbase + (long)d * 2048 + cc * 8, &Vb[buf][sb * 8]);
        }
    };

    stage_k(kh_b, 0);
    stage_v(vh_b, 0);
    __syncthreads();

    f32x4 o[4][2] = {};
    f32x4 osum[2] = {};
    bf16x8 ones;
    #pragma unroll
    for (int j = 0; j < 8; ++j) ones[j] = (short)0x3f80;  // bf16 1.0

    int vs = 1, vr = 0;  // V stage / read buffer (mod 3)
    for (int kt = 0; kt < 32; ++kt) {
        if (kt < 31) {
            stage_k(kh_b + (long)(kt + 1) * 64 * 64, (kt + 1) & 1);
            stage_v(vh_b + (kt + 1) * 64, vs);
        }

        const unsigned short* kb = Kb[kt & 1];
        f32x4 sa[2][4] = {};
        #pragma unroll
        for (int dd = 0; dd < 2; ++dd) {
            bf16x8 kf[4];
            #pragma unroll
            for (int ja = 0; ja < 4; ++ja) {
                int row = ja * 16 + l16;
                kf[ja] = *(const bf16x8*)(kb + (row * 8 + ((dd * 4 + quad) ^ (row & 7))) * 8);
            }
            #pragma unroll
            for (int i = 0; i < 2; ++i)
                #pragma unroll
                for (int ja = 0; ja < 4; ++ja)
                    sa[i][ja] = mfma16(kf[ja], qf[dd][i], sa[i][ja]);
        }

        #pragma unroll
        for (int i = 0; i < 2; ++i)
            #pragma unroll
            for (int ja = 0; ja < 4; ++ja)
                #pragma unroll
                for (int r = 0; r < 4; ++r)
                    sa[i][ja][r] = fexp2(sa[i][ja][r]);

        __syncthreads();  // K[kt+1]/V[kt+1] arrived; gates Kb/Vb buffer reuse

        const unsigned short* vb = Vb[vr];
        #pragma unroll
        for (int qtr = 0; qtr < 2; ++qtr) {
            #pragma unroll
            for (int jh = 0; jh < 2; ++jh)
                #pragma unroll
                for (int i = 0; i < 2; ++i) {
                    int row = w * 32 + i * 16 + l16;
                    int ja = qtr * 2 + jh;
                    uint2 pk;
                    pk.x = pkbf16(sa[i][ja][0], sa[i][ja][1]);
                    pk.y = pkbf16(sa[i][ja][2], sa[i][ja][3]);
                    *(uint2*)(&P[row * 44 + jh * 16 + quad * 4]) = pk;
                }
            bf16x8 vf[4], pf[2];
            #pragma unroll
            for (int jd = 0; jd < 4; ++jd) {
                int d = jd * 16 + l16;
                vf[jd] = *(const bf16x8*)(vb + (d * 8 + ((qtr * 4 + quad) ^ (d & 7))) * 8);
            }
            #pragma unroll
            for (int i = 0; i < 2; ++i) {
                int row = w * 32 + i * 16 + l16;
                pf[i] = *(const bf16x8*)(&P[row * 44 + quad * 8]);
            }
            #pragma unroll
            for (int jd = 0; jd < 4; ++jd)
                #pragma unroll
                for (int i = 0; i < 2; ++i)
                    o[jd][i] = mfma16(vf[jd], pf[i], o[jd][i]);
            #pragma unroll
            for (int i = 0; i < 2; ++i)
                osum[i] = mfma16(ones, pf[i], osum[i]);  // row-sum on MFMA pipe
        }

        vr = (vr + 1 == 3) ? 0 : vr + 1;
        vs = (vs + 1 == 3) ? 0 : vs + 1;
    }

    const int b = bh >> 4, hh = bh & 15;
    #pragma unroll
    for (int i = 0; i < 2; ++i) {
        float inv = 1.0f / osum[i][0];  // rows of osum all equal; col = l16 = q
        int s = qt * 128 + w * 32 + i * 16 + l16;
        #pragma unroll
        for (int jd = 0; jd < 4; ++jd) {
            uint2 pk;
            pk.x = pkbf16(o[jd][i][0] * inv, o[jd][i][1] * inv);
            pk.y = pkbf16(o[jd][i][2] * inv, o[jd][i][3] * inv);
            *(uint2*)(&ctx[((long)(b * 2048 + s) * 1024) + hh * 64 + jd * 16 + quad * 4]) = pk;
        }
    }
}

extern "C" void kernel_launch(void* const* d_in, const int* in_sizes, int n_in,
                              void* d_out, int out_size, void* d_ws, size_t ws_size,
                              hipStream_t stream) {
    const float* q  = (const float*)d_in[0];
    const float* k  = (const float*)d_in[1];
    const float* v  = (const float*)d_in[2];
    const float* wq = (const float*)d_in[3];
    const float* bq = (const float*)d_in[4];
    const float* wk = (const float*)d_in[5];
    const float* bk = (const float*)d_in[6];
    const float* wv = (const float*)d_in[7];
    const float* bv = (const float*)d_in[8];
    const float* wo = (const float*)d_in[9];
    const float* bo = (const float*)d_in[10];
    float* out = (float*)d_out;

    // workspace (u16 units): ab_q(8M, reused as ctx) | qh(8M) | kh(8M) |
    // vht(8M) | weights 4x1M  = 36M u16 = 72 MB.
    // ab_k/ab_v live in d_out (32 MB fp32 = 16M u16), dead until gemm_out.
    const size_t NE = 8u * 1024u * 1024u;
    unsigned short* ab_q = (unsigned short*)d_ws;
    unsigned short* qh   = ab_q + NE;
    unsigned short* kh   = qh + NE;
    unsigned short* vht  = kh + NE;
    unsigned short* wb   = vht + NE;
    unsigned short* wob  = wb + 3 * 1048576;
    unsigned short* ctx  = ab_q;
    unsigned short* ab_k = (unsigned short*)d_out;
    unsigned short* ab_v = ab_k + NE;

    dim3 blk(256);
    cvt_w<<<dim3(512, 4), blk, 0, stream>>>(wq, wk, wv, wo, wb);
    cvt3<<<dim3(4096, 3), blk, 0, stream>>>(q, k, v, ab_q, ab_k, ab_v);
    gemm_qkv<<<dim3(8, 64, 3), blk, 0, stream>>>(ab_q, ab_k, ab_v, wb,
                                                 bq, bk, bv, qh, kh, vht);
    attn<<<dim3(16, 64), blk, 0, stream>>>(qh, kh, vht, ctx);
    gemm_out<<<dim3(8, 64), blk, 0, stream>>>(ctx, wob, bo, out);
}

// Round 3
// 372.832 us; speedup vs baseline: 1.1264x; 1.0092x over previous
//
#include <hip/hip_runtime.h>

// MultiHeadAttentionBlock: B=4, S=2048, D=1024, H=16, DK=64
// Pipeline: cvt(w); cvt(q,k,v) [k,v staged in d_out - dead until final gemm];
// batched QKV gemm (1 dispatch, 1536 blocks); flash attention (transposed,
// no-max softmax); out gemm -> fp32.
// All matmuls: bf16 MFMA 16x16x32, fp32 accumulate, GLL16 staging.
//
// Verified MFMA layouts (learn_hip m89/m91):
//   A-operand: lane holds A[m=lane&15][k=(lane>>4)*8 + j], j=0..7 (16B contiguous)
//   B-operand: lane holds B^T-row n=lane&15 along k (same shape as A)
//   C/D:       col = lane&15 (B index), row = (lane>>4)*4 + reg (A index)

typedef __attribute__((ext_vector_type(8))) short bf16x8;
typedef __attribute__((ext_vector_type(4))) float f32x4;
typedef unsigned int u32;

#define DEVI __device__ __forceinline__

static constexpr int S_LEN = 2048;
static constexpr int NH = 16;
static constexpr int DK = 64;
// scores scale folded into Q projection: (1/sqrt(64)) * log2(e)
static constexpr float Q_SCALE = 0.125f * 1.44269504088896340736f;

DEVI unsigned short f2b(float f) {  // fp32 -> bf16 round-to-nearest-even
    unsigned int u = __builtin_bit_cast(unsigned int, f);
    u += 0x7fffu + ((u >> 16) & 1u);
    return (unsigned short)(u >> 16);
}

// pack two fp32 -> bf16x2 in one HW inst when available (gfx950 v_cvt_pk_bf16_f32)
DEVI u32 pkbf16(float a, float b) {
#if __has_builtin(__builtin_amdgcn_cvt_pk_bf16_f32)
    auto r = __builtin_amdgcn_cvt_pk_bf16_f32(a, b);
    return __builtin_bit_cast(u32, r);
#else
    return (u32)f2b(a) | ((u32)f2b(b) << 16);
#endif
}

// raw v_exp_f32: no OCML denormal/range fixup (inputs here are |x| <~ 12;
// denormal-result flush-to-zero is correct behavior for softmax weights)
DEVI float fexp2(float x) {
#if __has_builtin(__builtin_amdgcn_exp2f)
    return __builtin_amdgcn_exp2f(x);
#else
    return exp2f(x);
#endif
}

DEVI f32x4 mfma16(bf16x8 a, bf16x8 b, f32x4 c) {
    return __builtin_amdgcn_mfma_f32_16x16x32_bf16(a, b, c, 0, 0, 0);
}

#define GLL16(g, l)                                                        \
    __builtin_amdgcn_global_load_lds(                                      \
        (const __attribute__((address_space(1))) u32*)(g),                 \
        (__attribute__((address_space(3))) u32*)(l), 16, 0, 0)

// ---------------------------------------------------------------------------
// fp32 -> bf16 converters (memory-bound)
// ---------------------------------------------------------------------------
__global__ __launch_bounds__(256) void cvt3(
    const float* __restrict__ q, const float* __restrict__ k,
    const float* __restrict__ v, unsigned short* __restrict__ dq,
    unsigned short* __restrict__ dk, unsigned short* __restrict__ dv) {
    const int z = blockIdx.y;
    const float* src = z == 0 ? q : z == 1 ? k : v;
    unsigned short* dst = z == 0 ? dq : z == 1 ? dk : dv;
    long i = ((long)blockIdx.x * 256 + threadIdx.x) * 8;
    float4 v0 = *(const float4*)(src + i);
    float4 v1 = *(const float4*)(src + i + 4);
    uint4 o;
    o.x = pkbf16(v0.x, v0.y);
    o.y = pkbf16(v0.z, v0.w);
    o.z = pkbf16(v1.x, v1.y);
    o.w = pkbf16(v1.z, v1.w);
    *(uint4*)(dst + i) = o;
}

__global__ __launch_bounds__(256) void cvt_w(
    const float* __restrict__ a, const float* __restrict__ b,
    const float* __restrict__ c, const float* __restrict__ d,
    unsigned short* __restrict__ o) {
    const float* src = blockIdx.y == 0 ? a : blockIdx.y == 1 ? b
                     : blockIdx.y == 2 ? c : d;
    unsigned short* dst = o + (long)blockIdx.y * 1048576;
    long i = ((long)blockIdx.x * 256 + threadIdx.x) * 8;
    float4 v0 = *(const float4*)(src + i);
    float4 v1 = *(const float4*)(src + i + 4);
    uint4 ov;
    ov.x = pkbf16(v0.x, v0.y);
    ov.y = pkbf16(v0.z, v0.w);
    ov.z = pkbf16(v1.x, v1.y);
    ov.w = pkbf16(v1.z, v1.w);
    *(uint4*)(dst + i) = ov;
}

// ---------------------------------------------------------------------------
// Batched QKV GEMM: z=0: qh=(q@wq^T+bq)*Q_SCALE  [B,H,S,DK]
//                   z=1: kh= k@wk^T+bk           [B,H,S,DK]
//                   z=2: vht=(v@wv^T+bv)^T       [B,H,DK,S]
// 128x128 tile, BK=32, GLL16 double-buffered, XOR-swizzled LDS.
// ---------------------------------------------------------------------------
__global__ __launch_bounds__(256) void gemm_qkv(
    const unsigned short* __restrict__ aq, const unsigned short* __restrict__ ak,
    const unsigned short* __restrict__ av, const unsigned short* __restrict__ wqkv,
    const float* __restrict__ bq, const float* __restrict__ bk,
    const float* __restrict__ bv, unsigned short* __restrict__ qh,
    unsigned short* __restrict__ kh, unsigned short* __restrict__ vht) {
    __shared__ __align__(16) unsigned short As[2][128 * 32];
    __shared__ __align__(16) unsigned short Bs[2][128 * 32];
    const int tid = threadIdx.x;
    const int w = tid >> 6, l = tid & 63, l16 = l & 15, quad = l >> 4;
    const int wm = (w >> 1) * 64, wn = (w & 1) * 64;
    const int m0 = blockIdx.y * 128, n0 = blockIdx.x * 128;
    const int z = blockIdx.z;
    const unsigned short* A = z == 0 ? aq : z == 1 ? ak : av;
    const unsigned short* W = wqkv + (long)z * 1048576;
    const float* bias = z == 0 ? bq : z == 1 ? bk : bv;

    f32x4 acc[4][4] = {};

    auto stage = [&](int kt, int buf) {
        #pragma unroll
        for (int h = 0; h < 2; ++h) {
            int sb = h * 256 + w * 64;
            int slot = sb + l;
            int row = slot >> 2, c = (slot & 3) ^ ((row >> 1) & 3);
            GLL16(A + (long)(m0 + row) * 1024 + kt + c * 8, &As[buf][sb * 8]);
            GLL16(W + (long)(n0 + row) * 1024 + kt + c * 8, &Bs[buf][sb * 8]);
        }
    };

    stage(0, 0);
    __syncthreads();

    for (int ki = 0; ki < 32; ++ki) {
        if (ki < 31) stage((ki + 1) * 32, (ki + 1) & 1);
        const unsigned short* as = As[ki & 1];
        const unsigned short* bs = Bs[ki & 1];
        bf16x8 a[4], b[4];
        #pragma unroll
        for (int i = 0; i < 4; ++i) {
            int r = wm + i * 16 + l16;
            a[i] = *(const bf16x8*)(as + (r * 4 + (quad ^ ((r >> 1) & 3))) * 8);
        }
        #pragma unroll
        for (int j = 0; j < 4; ++j) {
            int r = wn + j * 16 + l16;
            b[j] = *(const bf16x8*)(bs + (r * 4 + (quad ^ ((r >> 1) & 3))) * 8);
        }
        #pragma unroll
        for (int i = 0; i < 4; ++i)
            #pragma unroll
            for (int j = 0; j < 4; ++j)
                acc[i][j] = mfma16(a[i], b[j], acc[i][j]);
        __syncthreads();  // drains GLL16 vmcnt + protects buf reuse
    }

    if (z < 2) {
        unsigned short* out = z == 0 ? qh : kh;
        const float scale = z == 0 ? Q_SCALE : 1.0f;
        #pragma unroll
        for (int j = 0; j < 4; ++j) {
            int n = n0 + wn + j * 16 + l16;
            float bvl = bias[n];
            int hh = n >> 6, dd = n & 63;
            #pragma unroll
            for (int i = 0; i < 4; ++i)
                #pragma unroll
                for (int r = 0; r < 4; ++r) {
                    int m = m0 + wm + i * 16 + quad * 4 + r;
                    int bb = m >> 11, ss = m & 2047;
                    out[(((long)(bb * NH + hh) * S_LEN + ss) * DK) + dd] =
                        f2b((acc[i][j][r] + bvl) * scale);
                }
        }
    } else {
        unsigned short* out = vht;  // [bh][d][s]
        #pragma unroll
        for (int j = 0; j < 4; ++j) {
            int n = n0 + wn + j * 16 + l16;
            float bvl = bias[n];
            int hh = n >> 6, dd = n & 63;
            #pragma unroll
            for (int i = 0; i < 4; ++i) {
                int m = m0 + wm + i * 16 + quad * 4;  // r=0..3 contiguous in s
                int bb = m >> 11, ss = m & 2047;
                uint2 pk;
                pk.x = pkbf16(acc[i][j][0] + bvl, acc[i][j][1] + bvl);
                pk.y = pkbf16(acc[i][j][2] + bvl, acc[i][j][3] + bvl);
                *(uint2*)(out + ((long)(bb * NH + hh) * DK + dd) * S_LEN + ss) = pk;
            }
        }
    }
}

// ---------------------------------------------------------------------------
// Output GEMM: fp32 out[m,n] = ctx@wo^T + bo
// ---------------------------------------------------------------------------
__global__ __launch_bounds__(256) void gemm_out(
    const unsigned short* __restrict__ A, const unsigned short* __restrict__ W,
    const float* __restrict__ bias, float* __restrict__ out) {
    __shared__ __align__(16) unsigned short As[2][128 * 32];
    __shared__ __align__(16) unsigned short Bs[2][128 * 32];
    const int tid = threadIdx.x;
    const int w = tid >> 6, l = tid & 63, l16 = l & 15, quad = l >> 4;
    const int wm = (w >> 1) * 64, wn = (w & 1) * 64;
    const int m0 = blockIdx.y * 128, n0 = blockIdx.x * 128;

    f32x4 acc[4][4] = {};

    auto stage = [&](int kt, int buf) {
        #pragma unroll
        for (int h = 0; h < 2; ++h) {
            int sb = h * 256 + w * 64;
            int slot = sb + l;
            int row = slot >> 2, c = (slot & 3) ^ ((row >> 1) & 3);
            GLL16(A + (long)(m0 + row) * 1024 + kt + c * 8, &As[buf][sb * 8]);
            GLL16(W + (long)(n0 + row) * 1024 + kt + c * 8, &Bs[buf][sb * 8]);
        }
    };

    stage(0, 0);
    __syncthreads();

    for (int ki = 0; ki < 32; ++ki) {
        if (ki < 31) stage((ki + 1) * 32, (ki + 1) & 1);
        const unsigned short* as = As[ki & 1];
        const unsigned short* bs = Bs[ki & 1];
        bf16x8 a[4], b[4];
        #pragma unroll
        for (int i = 0; i < 4; ++i) {
            int r = wm + i * 16 + l16;
            a[i] = *(const bf16x8*)(as + (r * 4 + (quad ^ ((r >> 1) & 3))) * 8);
        }
        #pragma unroll
        for (int j = 0; j < 4; ++j) {
            int r = wn + j * 16 + l16;
            b[j] = *(const bf16x8*)(bs + (r * 4 + (quad ^ ((r >> 1) & 3))) * 8);
        }
        #pragma unroll
        for (int i = 0; i < 4; ++i)
            #pragma unroll
            for (int j = 0; j < 4; ++j)
                acc[i][j] = mfma16(a[i], b[j], acc[i][j]);
        __syncthreads();
    }

    #pragma unroll
    for (int j = 0; j < 4; ++j) {
        int n = n0 + wn + j * 16 + l16;
        float bv = bias[n];
        #pragma unroll
        for (int i = 0; i < 4; ++i)
            #pragma unroll
            for (int r = 0; r < 4; ++r) {
                int m = m0 + wm + i * 16 + quad * 4 + r;
                out[(long)m * 1024 + n] = acc[i][j][r] + bv;
            }
    }
}

// ---------------------------------------------------------------------------
// Flash attention, transposed formulation.
//   S^T = K_tile . Q^T ; p = exp2(s) (Q pre-scaled, no max subtraction);
//   P 32-key halves through wave-private LDS rows; O^T = V^T . P^T.
//
// Round 3 changes (T4 counted-vmcnt; R2 left ~25% idle at the per-kt
// __syncthreads drain, which waits vmcnt(0) on loads issued THAT iteration):
//  - V staged 2 tiles ahead (triple buffer), K 1 ahead (double buffer).
//  - __syncthreads -> inline-asm `s_waitcnt vmcnt(2)` + raw s_barrier +
//    sched_barrier(0) (rule #18). Never drains to 0 in the main loop; the
//    newest V prefetch always stays in flight. Loads waited on have had a
//    full iteration (~500+ cyc) to land.
//  - Intra-kt barrier removed entirely: V[kt] is resident at iteration top,
//    so PV follows exp2 with no sync. One sync point per kt.
//  - Q fragments keep-alive'd pre-loop so the compiler's vmcnt wait for them
//    stays in the prologue.
//  - T5 s_setprio(1/0) around QK^T and PV MFMA clusters (m191: +4-7%).
// Drain math: prologue leaves V1 in flight; kt issues K[kt+1],V[kt+2];
// end-of-kt vmcnt(2) retires {V[kt+1],K[kt+1]}, keeps V[kt+2] flying.
// Tail: kt=30 waits vmcnt(0) (V31+K31), kt=31 no sync.
// LDS: 16384 (Kb x2) + 24576 (Vb x3) + 11264 (P) = 52224 B -> 3 blocks/CU.
// XCD swizzle kept (R1: FETCH 139->32 MB; now ~24.6 MB = compulsory).
// ---------------------------------------------------------------------------
__global__ __launch_bounds__(256, 3) void attn(
    const unsigned short* __restrict__ qh, const unsigned short* __restrict__ kh,
    const unsigned short* __restrict__ vht, unsigned short* __restrict__ ctx) {
    __shared__ __align__(16) unsigned short Kb[2][4096];   // [64 keys][64 d] swz
    __shared__ __align__(16) unsigned short Vb[3][4096];   // [64 d][64 keys] swz
    __shared__ __align__(16) unsigned short P[128 * 44];

    // XCD-aware swizzle: 1024 blocks, 1024 % 8 == 0 -> bijective.
    // 128 blocks/XCD = 8 heads x 16 q-tiles (head's K/V panel L2-resident).
    const int id = blockIdx.y * 16 + blockIdx.x;
    const int id2 = (id & 7) * 128 + (id >> 3);
    const int qt = id2 & 15, bh = id2 >> 4;
    const int tid = threadIdx.x;
    const int w = tid >> 6, l = tid & 63, l16 = l & 15, quad = l >> 4;

    const unsigned short* kh_b = kh + (long)bh * 2048 * 64;
    const unsigned short* vh_b = vht + (long)bh * 64 * 2048;

    const unsigned short* qsrc = qh + ((long)bh * 2048 + qt * 128) * 64;
    bf16x8 qf[2][2];
    #pragma unroll
    for (int dd = 0; dd < 2; ++dd)
        #pragma unroll
        for (int i = 0; i < 2; ++i)
            qf[dd][i] = *(const bf16x8*)(qsrc + (w * 32 + i * 16 + l16) * 64 +
                                         dd * 32 + quad * 8);
    // Force Q loads resolved here: compiler's vmcnt wait for qf lands in the
    // prologue, keeping the main loop free of compiler-inserted vmcnt.
    #pragma unroll
    for (int dd = 0; dd < 2; ++dd)
        #pragma unroll
        for (int i = 0; i < 2; ++i)
            asm volatile("" :: "v"(qf[dd][i]));

    // stage K tile (64 rows x 64 d = 512 slots of 16B, 2 per thread)
    auto stage_k = [&](const unsigned short* base, int buf) {
        #pragma unroll
        for (int rr = 0; rr < 2; ++rr) {
            int sb = rr * 256 + w * 64;
            int slot = sb + l;
            int row = slot >> 3, cc = (slot & 7) ^ (row & 7);
            GLL16(base + (long)row * 64 + cc * 8, &Kb[buf][sb * 8]);
        }
    };
    // stage V^T tile (64 d x 64 keys)
    auto stage_v = [&](const unsigned short* vbase, int buf) {
        #pragma unroll
        for (int rr = 0; rr < 2; ++rr) {
            int sb = rr * 256 + w * 64;
            int slot = sb + l;
            int d = slot >> 3, cc = (slot & 7) ^ (d & 7);
            GLL16(vbase + (long)d * 2048 + cc * 8, &Vb[buf][sb * 8]);
        }
    };

    // prologue: K0, V0, V1 issued; wait K0+V0 (vmcnt(2) leaves V1 in flight)
    stage_k(kh_b, 0);
    stage_v(vh_b, 0);
    stage_v(vh_b + 64, 1);
    asm volatile("s_waitcnt vmcnt(2)" ::: "memory");
    __builtin_amdgcn_s_barrier();
    __builtin_amdgcn_sched_barrier(0);

    f32x4 o[4][2] = {};
    f32x4 osum[2] = {};
    bf16x8 ones;
    #pragma unroll
    for (int j = 0; j < 8; ++j) ones[j] = (short)0x3f80;  // bf16 1.0

    const unsigned short* kstage = kh_b + 64 * 64;   // K[1] base
    const unsigned short* vstage = vh_b + 2 * 64;    // V[2] base
    int vr = 0, vs = 2;  // V read / stage buffer (mod 3)
    for (int kt = 0; kt < 32; ++kt) {
        if (kt < 31) stage_k(kstage, (kt + 1) & 1);
        if (kt < 30) stage_v(vstage, vs);
        kstage += 64 * 64;
        vstage += 64;
        __builtin_amdgcn_sched_barrier(0);  // keep prefetch issue at loop top

        const unsigned short* kb = Kb[kt & 1];
        f32x4 sa[2][4] = {};
        #pragma unroll
        for (int dd = 0; dd < 2; ++dd) {
            bf16x8 kf[4];
            #pragma unroll
            for (int ja = 0; ja < 4; ++ja) {
                int row = ja * 16 + l16;
                kf[ja] = *(const bf16x8*)(kb + (row * 8 + ((dd * 4 + quad) ^ (row & 7))) * 8);
            }
            __builtin_amdgcn_s_setprio(1);
            #pragma unroll
            for (int i = 0; i < 2; ++i)
                #pragma unroll
                for (int ja = 0; ja < 4; ++ja)
                    sa[i][ja] = mfma16(kf[ja], qf[dd][i], sa[i][ja]);
            __builtin_amdgcn_s_setprio(0);
        }

        #pragma unroll
        for (int i = 0; i < 2; ++i)
            #pragma unroll
            for (int ja = 0; ja < 4; ++ja)
                #pragma unroll
                for (int r = 0; r < 4; ++r)
                    sa[i][ja][r] = fexp2(sa[i][ja][r]);

        // no barrier: V[kt] resident since end of kt-1; Vb[vs] being written
        // is a different buffer ((kt+2)%3 != kt%3).
        const unsigned short* vb = Vb[vr];
        #pragma unroll
        for (int qtr = 0; qtr < 2; ++qtr) {
            #pragma unroll
            for (int jh = 0; jh < 2; ++jh)
                #pragma unroll
                for (int i = 0; i < 2; ++i) {
                    int row = w * 32 + i * 16 + l16;
                    int ja = qtr * 2 + jh;
                    uint2 pk;
                    pk.x = pkbf16(sa[i][ja][0], sa[i][ja][1]);
                    pk.y = pkbf16(sa[i][ja][2], sa[i][ja][3]);
                    *(uint2*)(&P[row * 44 + jh * 16 + quad * 4]) = pk;
                }
            bf16x8 vf[4], pf[2];
            #pragma unroll
            for (int jd = 0; jd < 4; ++jd) {
                int d = jd * 16 + l16;
                vf[jd] = *(const bf16x8*)(vb + (d * 8 + ((qtr * 4 + quad) ^ (d & 7))) * 8);
            }
            #pragma unroll
            for (int i = 0; i < 2; ++i) {
                int row = w * 32 + i * 16 + l16;
                pf[i] = *(const bf16x8*)(&P[row * 44 + quad * 8]);
            }
            __builtin_amdgcn_s_setprio(1);
            #pragma unroll
            for (int jd = 0; jd < 4; ++jd)
                #pragma unroll
                for (int i = 0; i < 2; ++i)
                    o[jd][i] = mfma16(vf[jd], pf[i], o[jd][i]);
            #pragma unroll
            for (int i = 0; i < 2; ++i)
                osum[i] = mfma16(ones, pf[i], osum[i]);  // row-sum on MFMA pipe
            __builtin_amdgcn_s_setprio(0);
        }

        // end-of-kt sync: wait K[kt+1]+V[kt+1] landed, keep V[kt+2] in flight
        if (kt < 30) {
            asm volatile("s_waitcnt vmcnt(2)" ::: "memory");
        } else if (kt == 30) {
            asm volatile("s_waitcnt vmcnt(0)" ::: "memory");
        }
        if (kt < 31) {
            __builtin_amdgcn_s_barrier();
            __builtin_amdgcn_sched_barrier(0);
        }

        vr = (vr + 1 == 3) ? 0 : vr + 1;
        vs = (vs + 1 == 3) ? 0 : vs + 1;
    }

    const int b = bh >> 4, hh = bh & 15;
    #pragma unroll
    for (int i = 0; i < 2; ++i) {
        float inv = 1.0f / osum[i][0];  // rows of osum all equal; col = l16 = q
        int s = qt * 128 + w * 32 + i * 16 + l16;
        #pragma unroll
        for (int jd = 0; jd < 4; ++jd) {
            uint2 pk;
            pk.x = pkbf16(o[jd][i][0] * inv, o[jd][i][1] * inv);
            pk.y = pkbf16(o[jd][i][2] * inv, o[jd][i][3] * inv);
            *(uint2*)(&ctx[((long)(b * 2048 + s) * 1024) + hh * 64 + jd * 16 + quad * 4]) = pk;
        }
    }
}

extern "C" void kernel_launch(void* const* d_in, const int* in_sizes, int n_in,
                              void* d_out, int out_size, void* d_ws, size_t ws_size,
                              hipStream_t stream) {
    const float* q  = (const float*)d_in[0];
    const float* k  = (const float*)d_in[1];
    const float* v  = (const float*)d_in[2];
    const float* wq = (const float*)d_in[3];
    const float* bq = (const float*)d_in[4];
    const float* wk = (const float*)d_in[5];
    const float* bk = (const float*)d_in[6];
    const float* wv = (const float*)d_in[7];
    const float* bv = (const float*)d_in[8];
    const float* wo = (const float*)d_in[9];
    const float* bo = (const float*)d_in[10];
    float* out = (float*)d_out;

    // workspace (u16 units): ab_q(8M, reused as ctx) | qh(8M) | kh(8M) |
    // vht(8M) | weights 4x1M  = 36M u16 = 72 MB.
    // ab_k/ab_v live in d_out (32 MB fp32 = 16M u16), dead until gemm_out.
    const size_t NE = 8u * 1024u * 1024u;
    unsigned short* ab_q = (unsigned short*)d_ws;
    unsigned short* qh   = ab_q + NE;
    unsigned short* kh   = qh + NE;
    unsigned short* vht  = kh + NE;
    unsigned short* wb   = vht + NE;
    unsigned short* wob  = wb + 3 * 1048576;
    unsigned short* ctx  = ab_q;
    unsigned short* ab_k = (unsigned short*)d_out;
    unsigned short* ab_v = ab_k + NE;

    dim3 blk(256);
    cvt_w<<<dim3(512, 4), blk, 0, stream>>>(wq, wk, wv, wo, wb);
    cvt3<<<dim3(4096, 3), blk, 0, stream>>>(q, k, v, ab_q, ab_k, ab_v);
    gemm_qkv<<<dim3(8, 64, 3), blk, 0, stream>>>(ab_q, ab_k, ab_v, wb,
                                                 bq, bk, bv, qh, kh, vht);
    attn<<<dim3(16, 64), blk, 0, stream>>>(qh, kh, vht, ctx);
    gemm_out<<<dim3(8, 64), blk, 0, stream>>>(ctx, wob, bo, out);
}